// Round 7
// baseline (245.279 us; speedup 1.0000x reference)
//
#include <hip/hip_runtime.h>

// Problem constants: B=4, S=2048, D=1024
#define BB 4
#define SS 2048
#define DD 1024

typedef __attribute__((ext_vector_type(8))) _Float16 half8;
typedef __attribute__((ext_vector_type(4))) float f32x4;
typedef unsigned short ushort_t;

// fp32 -> fp16 (RTN via v_cvt_f16_f32), returned as raw bits
__device__ __forceinline__ ushort_t f2h(float f) {
    union { _Float16 h; ushort_t u; } c;
    c.h = (_Float16)f;
    return c.u;
}

union Pack8 { ushort_t u[8]; uint4 v; };

// ---------------------------------------------------------------------------
// K0: fp32 -> fp16 convert for BOTH Q(enc) and K(att) in one launch.
// ---------------------------------------------------------------------------
__global__ __launch_bounds__(256) void conv_h_qk(const float* __restrict__ enc,
                                                 const float* __restrict__ att,
                                                 ushort_t* __restrict__ Qb,
                                                 ushort_t* __restrict__ Kb) {
    const float* in = blockIdx.y ? att : enc;
    ushort_t* out   = blockIdx.y ? Kb : Qb;
    long i = ((long)blockIdx.x * 256 + threadIdx.x) * 8;
    float4 a = *(const float4*)(in + i);
    float4 b = *(const float4*)(in + i + 4);
    Pack8 p;
    p.u[0] = f2h(a.x); p.u[1] = f2h(a.y); p.u[2] = f2h(a.z); p.u[3] = f2h(a.w);
    p.u[4] = f2h(b.x); p.u[5] = f2h(b.y); p.u[6] = f2h(b.z); p.u[7] = f2h(b.w);
    *(uint4*)(out + i) = p.v;
}

// ---------------------------------------------------------------------------
// Pipelined GEMM (bt form): C[m][n] = sum_k A[m][k]*B[n][k], fp16 in, fp32 out.
// BM=256, BN=128, BK=64. 8 waves (512 thr), wave grid 2m x 4n, per-wave out
// 128x32 (acc[8][2]). THREE LDS K-tile buffers (3 x 48KB = 144KB):
//   compute tile j from buf(j%3) while staging tile j+2 into buf((j+2)%3)
//   -> writer buffer always disjoint from both live reader buffers => no
//      LDS overwrite race by construction.
// Counted vmcnt: at each K-tile end, s_waitcnt vmcnt(6) (this tile's 6
// prefetch loads may stay in flight; everything older -> done). Never 0
// in steady state (T4). 16 MFMA per phase in setprio(1) (T5). Proven
// 3-bit XOR swizzle on both sides (T2, measured 0 conflicts).
// ---------------------------------------------------------------------------
#define SBUF 49152   // per-buffer: A 32768 + B 16384

template<int NKT>
__global__ __launch_bounds__(512, 1)
void gemm8p(const ushort_t* __restrict__ A, const ushort_t* __restrict__ Bm,
            float* __restrict__ C, int N, int NTN,
            long sAb, long sBb, long sCb) {
    extern __shared__ char lds[];
    const int Kd = NKT * 64;
    const int t = threadIdx.x;
    const int w = t >> 6, lane = t & 63;
    const int wr = w >> 2, wc = w & 3;

    // XCD-aware bijective swizzle (nwg % 8 == 0 for both instantiations)
    const int nwg = gridDim.x;
    const int cpx = nwg >> 3;
    const int lid = blockIdx.x;
    const int swz = (lid & 7) * cpx + (lid >> 3);
    const int per_b = NTN << 3;           // 8 m-tiles x NTN n-tiles
    const int bz  = swz / per_b;
    const int rem = swz - bz * per_b;
    const int m0 = (rem & 7) << 8;
    const int n0 = (rem >> 3) << 7;

    const ushort_t* Ab = A + (long)bz * sAb + (long)m0 * Kd;
    const ushort_t* Bb = Bm + (long)bz * sBb + (long)n0 * Kd;
    float* Cb = C + (long)bz * sCb;

    f32x4 acc[8][2];
    #pragma unroll
    for (int i = 0; i < 8; ++i)
        #pragma unroll
        for (int j = 0; j < 2; ++j) acc[i][j] = f32x4{0.f, 0.f, 0.f, 0.f};

    // staging lane constants (identical to the verified gemm_bt pattern)
    const int srow  = lane >> 3;                          // row within 8-row chunk
    const int schnk = ((lane & 7) << 4) ^ (srow << 4);    // inverse-swizzled src col

    auto STAGE_A = [&](int kt, char* bufb, int jj) {
        int bb = jj * 8 + w;                              // 1KB block 0..31
        int r  = bb * 8 + srow;                           // tile row 0..255
        const char* src = (const char*)(Ab + (long)r * Kd + kt * 64) + schnk;
        __builtin_amdgcn_global_load_lds(
            (__attribute__((address_space(1))) void*)src,
            (__attribute__((address_space(3))) void*)(bufb + (bb << 10)),
            16, 0, 0);
    };
    auto STAGE_B = [&](int kt, char* bufb, int jj) {
        int bb = jj * 8 + w;                              // 1KB block 0..15
        int r  = bb * 8 + srow;                           // tile row 0..127
        const char* src = (const char*)(Bb + (long)r * Kd + kt * 64) + schnk;
        __builtin_amdgcn_global_load_lds(
            (__attribute__((address_space(1))) void*)src,
            (__attribute__((address_space(3))) void*)(bufb + 32768 + (bb << 10)),
            16, 0, 0);
    };

    const int lar    = lane & 15;
    const int colhib = (lane >> 4) << 4;                  // (lane>>4)*8 elems *2B

    // One phase: ds-read fragments (tile in cb, k-slice kk) || stage half of
    // tile skt into sb || optional counted vmcnt || barrier || 16 MFMA || barrier.
    auto PHASE = [&](char* cb, int kk, int skt, char* sb, bool dostage, int vm) {
        half8 af[8]; half8 bf[2];
        const int colb = (kk << 6) | colhib;              // byte col base in 128B row
        #pragma unroll
        for (int fm = 0; fm < 8; ++fm) {
            int rA = (wr << 7) + (fm << 4) + lar;
            af[fm] = *(const half8*)(cb + (rA << 7) + (colb ^ ((rA & 7) << 4)));
        }
        #pragma unroll
        for (int fn = 0; fn < 2; ++fn) {
            int rB = (wc << 5) + (fn << 4) + lar;
            bf[fn] = *(const half8*)(cb + 32768 + (rB << 7) + (colb ^ ((rB & 7) << 4)));
        }
        if (dostage) {
            if (kk == 0) { STAGE_A(skt, sb, 0); STAGE_A(skt, sb, 1); STAGE_B(skt, sb, 0); }
            else         { STAGE_A(skt, sb, 2); STAGE_A(skt, sb, 3); STAGE_B(skt, sb, 1); }
        }
        if (vm == 6)      asm volatile("s_waitcnt vmcnt(6)" ::: "memory");
        else if (vm == 0) asm volatile("s_waitcnt vmcnt(0)" ::: "memory");
        __builtin_amdgcn_s_barrier();
        __builtin_amdgcn_s_setprio(1);
        #pragma unroll
        for (int fm = 0; fm < 8; ++fm)
            #pragma unroll
            for (int fn = 0; fn < 2; ++fn)
                acc[fm][fn] = __builtin_amdgcn_mfma_f32_16x16x32_f16(
                    af[fm], bf[fn], acc[fm][fn], 0, 0, 0);
        __builtin_amdgcn_s_setprio(0);
        __builtin_amdgcn_s_barrier();
    };

    // Prologue: tiles 0,1 -> bufs 0,1; wait all of tile 0 (tile 1 may fly).
    char* b0 = lds;
    char* b1 = lds + SBUF;
    char* b2 = lds + 2 * SBUF;
    STAGE_A(0, b0, 0); STAGE_A(0, b0, 1); STAGE_A(0, b0, 2); STAGE_A(0, b0, 3);
    STAGE_B(0, b0, 0); STAGE_B(0, b0, 1);
    STAGE_A(1, b1, 0); STAGE_A(1, b1, 1); STAGE_A(1, b1, 2); STAGE_A(1, b1, 3);
    STAGE_B(1, b1, 0); STAGE_B(1, b1, 1);
    asm volatile("s_waitcnt vmcnt(6)" ::: "memory");
    __builtin_amdgcn_s_barrier();

    char *cb = b0, *nb = b1, *sb = b2;
    for (int j = 0; j < NKT - 2; ++j) {
        PHASE(cb, 0, j + 2, sb, true, -1);
        PHASE(cb, 1, j + 2, sb, true, 6);       // tile j+1 guaranteed complete
        char* tmp = cb; cb = nb; nb = sb; sb = tmp;
    }
    // tile NKT-2: nothing left to stage; drain fully before final tile
    PHASE(cb, 0, 0, sb, false, -1);
    PHASE(cb, 1, 0, sb, false, 0);
    { char* tmp = cb; cb = nb; nb = sb; sb = tmp; }
    // tile NKT-1
    PHASE(cb, 0, 0, sb, false, -1);
    PHASE(cb, 1, 0, sb, false, -1);

    // epilogue: D row = (lane>>4)*4 + q, col = lane&15  [m89 verified layout]
    #pragma unroll
    for (int fm = 0; fm < 8; ++fm) {
        int mrow = m0 + (wr << 7) + (fm << 4) + ((lane >> 4) << 2);
        #pragma unroll
        for (int fn = 0; fn < 2; ++fn) {
            int ncol = n0 + (wc << 5) + (fn << 4) + (lane & 15);
            #pragma unroll
            for (int q = 0; q < 4; ++q)
                Cb[(long)(mrow + q) * N + ncol] = acc[fm][fn][q];
        }
    }
}

// ---------------------------------------------------------------------------
// K2: row softmax over k (2048 fp32), write P as fp16 in-place over the row.
// ---------------------------------------------------------------------------
__device__ __forceinline__ float wred_max(float v) {
    #pragma unroll
    for (int o = 32; o > 0; o >>= 1) v = fmaxf(v, __shfl_xor(v, o, 64));
    return v;
}
__device__ __forceinline__ float wred_sum(float v) {
    #pragma unroll
    for (int o = 32; o > 0; o >>= 1) v += __shfl_xor(v, o, 64);
    return v;
}

__global__ __launch_bounds__(256) void softmax_rows(float* __restrict__ score) {
    __shared__ float red[4];
    __shared__ float bc[2];
    const long row = blockIdx.x;
    float* rp = score + row * (long)SS;
    const int t = threadIdx.x, w = t >> 6, lane = t & 63;

    float4 v0 = ((const float4*)rp)[t * 2];
    float4 v1 = ((const float4*)rp)[t * 2 + 1];
    float f[8] = {v0.x, v0.y, v0.z, v0.w, v1.x, v1.y, v1.z, v1.w};

    float m = f[0];
    #pragma unroll
    for (int j = 1; j < 8; ++j) m = fmaxf(m, f[j]);
    m = wred_max(m);
    if (lane == 0) red[w] = m;
    __syncthreads();
    if (t == 0) bc[0] = fmaxf(fmaxf(red[0], red[1]), fmaxf(red[2], red[3]));
    __syncthreads();
    m = bc[0];

    float e[8], s = 0.f;
    #pragma unroll
    for (int j = 0; j < 8; ++j) { e[j] = __expf(f[j] - m); s += e[j]; }
    s = wred_sum(s);
    if (lane == 0) red[w] = s;
    __syncthreads();
    if (t == 0) bc[1] = red[0] + red[1] + red[2] + red[3];
    __syncthreads();
    const float inv = 1.f / bc[1];

    Pack8 p;
    #pragma unroll
    for (int j = 0; j < 8; ++j) p.u[j] = f2h(e[j] * inv);
    ((uint4*)rp)[t] = p.v;
}

// ---------------------------------------------------------------------------
// K3: transpose P: Pt[b][n][q] = P[b][q][n] (fp16 bits in score buffer).
// ---------------------------------------------------------------------------
__global__ __launch_bounds__(256) void transposeP(const ushort_t* __restrict__ Pb,
                                                  ushort_t* __restrict__ Pt) {
    __shared__ ushort_t lds[64][72];
    const int b = blockIdx.z;
    const int n0 = blockIdx.x << 6, q0 = blockIdx.y << 6;
    const int t = threadIdx.x, rh = t >> 3, cb = (t & 7) << 3;

    #pragma unroll
    for (int it = 0; it < 2; ++it) {
        int r = (it << 5) + rh;
        const ushort_t* src = Pb + ((long)(b * SS + q0 + r)) * 4096 + n0 + cb;
        *(uint4*)&lds[r][cb] = *(const uint4*)src;
    }
    __syncthreads();
    #pragma unroll
    for (int it = 0; it < 2; ++it) {
        int rr = (it << 5) + rh;
        Pack8 p;
        #pragma unroll
        for (int j = 0; j < 8; ++j) p.u[j] = lds[cb + j][rr];
        *(uint4*)(Pt + ((long)b * SS + n0 + rr) * (long)SS + q0 + cb) = p.v;
    }
}

// ---------------------------------------------------------------------------
// K4: Xbt[b][d][q] = fp16(enc[b][q][d] + res[b][q][d])
// ---------------------------------------------------------------------------
__global__ __launch_bounds__(256) void transposeX(const float* __restrict__ enc,
                                                  const float* __restrict__ res,
                                                  ushort_t* __restrict__ Xbt) {
    __shared__ ushort_t lds[64][72];
    const int b = blockIdx.z;
    const int q0 = blockIdx.x << 6, d0 = blockIdx.y << 6;
    const int t = threadIdx.x, rh = t >> 3, cb = (t & 7) << 3;

    #pragma unroll
    for (int it = 0; it < 2; ++it) {
        int r = (it << 5) + rh;
        long base = ((long)b * SS + q0 + r) * (long)DD + d0 + cb;
        float4 a0 = *(const float4*)(enc + base);
        float4 a1 = *(const float4*)(enc + base + 4);
        float4 b0 = *(const float4*)(res + base);
        float4 b1 = *(const float4*)(res + base + 4);
        Pack8 p;
        p.u[0] = f2h(a0.x + b0.x); p.u[1] = f2h(a0.y + b0.y);
        p.u[2] = f2h(a0.z + b0.z); p.u[3] = f2h(a0.w + b0.w);
        p.u[4] = f2h(a1.x + b1.x); p.u[5] = f2h(a1.y + b1.y);
        p.u[6] = f2h(a1.z + b1.z); p.u[7] = f2h(a1.w + b1.w);
        *(uint4*)&lds[r][cb] = p.v;
    }
    __syncthreads();
    #pragma unroll
    for (int it = 0; it < 2; ++it) {
        int rr = (it << 5) + rh;
        Pack8 p;
        #pragma unroll
        for (int j = 0; j < 8; ++j) p.u[j] = lds[cb + j][rr];
        *(uint4*)(Xbt + ((long)b * DD + d0 + rr) * (long)SS + q0 + cb) = p.v;
    }
}

// ---------------------------------------------------------------------------
// Workspace layout (96 MiB, overlapped lifetimes):
//   [0, 64 MiB)   score fp32 -> (after transposeP) Xbt fp16 [B][D][S]
//   [64, 96 MiB)  Qb + Kb fp16 -> (after GEMM1) Pt fp16 [B][S][S]
// ---------------------------------------------------------------------------
extern "C" void kernel_launch(void* const* d_in, const int* in_sizes, int n_in,
                              void* d_out, int out_size, void* d_ws, size_t ws_size,
                              hipStream_t stream) {
    const float* enc = (const float*)d_in[0];
    const float* att = (const float*)d_in[1];
    const float* res = (const float*)d_in[2];
    float* out = (float*)d_out;
    char* ws = (char*)d_ws;

    float*    score = (float*)ws;
    ushort_t* Qb    = (ushort_t*)(ws + 67108864);
    ushort_t* Kb    = (ushort_t*)(ws + 67108864 + 16777216);
    ushort_t* Pt    = (ushort_t*)(ws + 67108864);   // overlays Qb/Kb
    ushort_t* Xbt   = (ushort_t*)ws;                // overlays score

    // opt in to 144KB dynamic LDS (host-side attribute set; capture-safe)
    hipFuncSetAttribute(reinterpret_cast<const void*>(&gemm8p<16>),
                        hipFuncAttributeMaxDynamicSharedMemorySize, 3 * SBUF);
    hipFuncSetAttribute(reinterpret_cast<const void*>(&gemm8p<32>),
                        hipFuncAttributeMaxDynamicSharedMemorySize, 3 * SBUF);

    // K0: convert Q (enc) and K (att) to fp16
    conv_h_qk<<<dim3(4096, 2), 256, 0, stream>>>(enc, att, Qb, Kb);

    // K1: score[b][q][k] = Q . K   (M=2048, N=2048, Kd=1024; 8x16 tiles x4)
    gemm8p<16><<<512, 512, 3 * SBUF, stream>>>(
        Qb, Kb, score, SS, 16,
        (long)SS * DD, (long)SS * DD, (long)SS * SS);

    // K2: softmax rows, P fp16 in place
    softmax_rows<<<BB * SS, 256, 0, stream>>>(score);

    // K3: Pt[b][k][q] = P[b][q][k]
    transposeP<<<dim3(32, 32, BB), 256, 0, stream>>>((const ushort_t*)score, Pt);

    // K4: Xbt[b][d][q] = fp16(enc + res)
    transposeX<<<dim3(32, 16, BB), 256, 0, stream>>>(enc, res, Xbt);

    // K5: out[b][k][d] = sum_q Pt[k][q] * Xbt[d][q] (M=2048, N=1024, Kd=2048)
    gemm8p<32><<<256, 512, 3 * SBUF, stream>>>(
        Pt, Xbt, out, DD, 8,
        (long)SS * SS, (long)DD * SS, (long)SS * DD);
}